// Round 18
// baseline (845.926 us; speedup 1.0000x reference)
//
#include <hip/hip_runtime.h>
#include <hip/hip_bf16.h>

#define NN 100000
#define EE 600000
#define RR 3
#define INF 256
#define HFF 256
#define NH 4
#define DD 64
#define CC 153
#define NB 98    // ceil(NN/1024)
#define ROWG 196 // row-groups; each block loops 4 panels (196*4=784 >= 782)

typedef __attribute__((ext_vector_type(8))) _Float16 f16x8;
typedef __attribute__((ext_vector_type(2))) _Float16 h2f16;
typedef __attribute__((ext_vector_type(4))) float f32x4;

#define GLDS(g, l) __builtin_amdgcn_global_load_lds((const __attribute__((address_space(1))) void*)(g), \
                                                    (__attribute__((address_space(3))) void*)(l), 16, 0, 0)

static __device__ __forceinline__ unsigned short f2h(float x) {
    _Float16 h = (_Float16)x;
    return __builtin_bit_cast(unsigned short, h);
}
static __device__ __forceinline__ float h2f(unsigned short u) {
    return (float)__builtin_bit_cast(_Float16, u);
}

// ============ f16 MFMA GEMM, 128x128 tile, BK=64, 4 waves, PERSISTENT ========
// Each block loops over 4 row panels (bm = (blockIdx.y + 196*i)*128) so the
// K-pipeline runs 16 steps/block instead of 4 (amortizes fill+drain stalls).
// Grid x = col tile (fastest) so blocks sharing an A panel dispatch adjacently.
// GM=0: C32[M,CC] = A@Bt + bias  (final linear), grid (2,196)
// GM=1: merged 3-relation projection, grid (6,196); Bt=[768][256];
//       fp16 feat via LDS-staged coalesced store; fused el/er epilogue.
template<int GM>
__global__ __launch_bounds__(256) void mfma_gemm(const unsigned short* __restrict__ A,
                                                 const unsigned short* __restrict__ Bt,
                                                 const float* __restrict__ bias,
                                                 float* __restrict__ C32,
                                                 unsigned short* __restrict__ C16,
                                                 const float* __restrict__ al,
                                                 const float* __restrict__ ar,
                                                 float* __restrict__ el,
                                                 float* __restrict__ er,
                                                 int M) {
    __shared__ __align__(1024) char lds[32768];   // A tile 16KB | B tile 16KB
    const int tid = threadIdx.x;
    const int lane = tid & 63;
    const int w = tid >> 6;
    const int wr = w >> 1, wc = w & 1;
    const int bn = blockIdx.x * 128;

    const int lrow8 = lane >> 3;
    const int cbs = ((lane & 7) << 4) ^ ((lrow8 & 7) << 4);
    const int cbase = w * 8;
    const bool isA = (w < 2);

    const char* gA = (const char*)A;
    const char* gB = (const char*)Bt;

    for (int mi = 0; mi < 4; ++mi) {
        const int bm = (blockIdx.y + ROWG * mi) * 128;
        if (bm >= M) continue;                   // uniform per block

        f32x4 acc[4][4] = {};

        for (int step = 0; step < 4; ++step) {
            const int k0b = step * 128;          // 64 f16 per K-step
#pragma unroll
            for (int i = 0; i < 8; ++i) {
                int c = cbase + i;
                char* lptr = &lds[c * 1024];
                if (isA) {
                    int R = c * 8 + lrow8;
                    int grow = bm + R; if (grow >= M) grow = M - 1;
                    GLDS(gA + (size_t)grow * 512 + k0b + cbs, lptr);
                } else {
                    int nIdx = (c - 16) * 8 + lrow8;
                    GLDS(gB + (size_t)(bn + nIdx) * 512 + k0b + cbs, lptr);
                }
            }
            __syncthreads();
#pragma unroll
            for (int kk = 0; kk < 2; ++kk) {
                f16x8 af[4], bfr[4];
                const int o = kk * 64 + ((lane >> 4) << 4);
#pragma unroll
                for (int m = 0; m < 4; ++m) {
                    int R = wr * 64 + m * 16 + (lane & 15);
                    af[m] = *reinterpret_cast<const f16x8*>(&lds[R * 128 + (o ^ ((R & 7) << 4))]);
                }
#pragma unroll
                for (int n = 0; n < 4; ++n) {
                    int Rn = wc * 64 + n * 16 + (lane & 15);
                    bfr[n] = *reinterpret_cast<const f16x8*>(&lds[16384 + Rn * 128 + (o ^ ((Rn & 7) << 4))]);
                }
#pragma unroll
                for (int m = 0; m < 4; ++m)
#pragma unroll
                    for (int n = 0; n < 4; ++n)
                        acc[m][n] = __builtin_amdgcn_mfma_f32_16x16x32_f16(af[m], bfr[n], acc[m][n], 0, 0, 0);
            }
            __syncthreads();
        }

        const int rb = bm + wr * 64 + ((lane >> 4) << 2);

        if (GM == 0) {
            const int cb2 = bn + wc * 64 + (lane & 15);
#pragma unroll
            for (int m = 0; m < 4; ++m)
#pragma unroll
                for (int n = 0; n < 4; ++n) {
                    int col = cb2 + n * 16;
                    if (col < CC) {
                        float bb = bias[col];
#pragma unroll
                        for (int j = 0; j < 4; ++j) {
                            int row = rb + m * 16 + j;
                            if (row < M) C32[(size_t)row * CC + col] = acc[m][n][j] + bb;
                        }
                    }
                }
            // next panel's staging writes LDS; K-loop's final barrier already
            // synced all waves, and this epilogue doesn't read LDS.
        } else {
            // ---- fused el/er: wave's 64 cols == one head of one relation ----
            const int c0 = bn + wc * 64;
            const int rh = c0 >> 6;              // r*4 + h, 0..11
            const int rw = rh >> 2;
            const int h  = rh & 3;
            float alv[4], arv[4];
#pragma unroll
            for (int n = 0; n < 4; ++n) {
                alv[n] = al[rh * 64 + n * 16 + (lane & 15)];
                arv[n] = ar[rh * 64 + n * 16 + (lane & 15)];
            }
#pragma unroll
            for (int m = 0; m < 4; ++m)
#pragma unroll
                for (int j = 0; j < 4; ++j) {
                    float pl = acc[m][0][j] * alv[0] + acc[m][1][j] * alv[1]
                             + acc[m][2][j] * alv[2] + acc[m][3][j] * alv[3];
                    float pr = acc[m][0][j] * arv[0] + acc[m][1][j] * arv[1]
                             + acc[m][2][j] * arv[2] + acc[m][3][j] * arv[3];
#pragma unroll
                    for (int o2 = 1; o2 < 16; o2 <<= 1) {
                        pl += __shfl_xor(pl, o2);
                        pr += __shfl_xor(pr, o2);
                    }
                    int row = rb + m * 16 + j;
                    if ((lane & 15) == 0 && row < M) {
                        el[(size_t)rw * NN * 4 + row * 4 + h] = pl;
                        er[(size_t)rw * NN * 4 + row * 4 + h] = pr;
                    }
                }
            // ---- fp16 feat: stage in LDS (XOR swizzle), store coalesced ----
            __syncthreads();   // all MFMA LDS reads done; safe to reuse lds
            unsigned short* l16 = (unsigned short*)lds;
#pragma unroll
            for (int m = 0; m < 4; ++m)
#pragma unroll
                for (int n = 0; n < 4; ++n)
#pragma unroll
                    for (int j = 0; j < 4; ++j) {
                        int row = wr * 64 + m * 16 + ((lane >> 4) << 2) + j;
                        int colb = (wc * 64 + n * 16 + (lane & 15)) * 2;
                        int addr = row * 256 + (colb ^ (((row >> 2) & 7) << 5));
                        l16[addr >> 1] = f2h(acc[m][n][j]);
                    }
            __syncthreads();
            const int rblk = bn >> 8;            // relation of this tile
            const int bnc  = bn & 255;           // col base within relation
            const size_t NFE = (size_t)NN * 256;
#pragma unroll
            for (int i = 0; i < 8; ++i) {
                int seg = w * 8 + i;             // 0..31, 1KB segments
                int row = seg * 4 + (lane >> 4);
                int colb = (lane & 15) * 16;
                int addr = row * 256 + (colb ^ (((row >> 2) & 7) << 5));
                uint4 v = *reinterpret_cast<const uint4*>(&lds[addr]);
                int grow = bm + row;
                if (grow < M) {
                    unsigned short* gp = C16 + (size_t)rblk * NFE + (size_t)grow * 256 + bnc + (lane & 15) * 8;
                    *reinterpret_cast<uint4*>(gp) = v;
                }
            }
            __syncthreads();   // epilogue LDS reads done before next panel stages
        }
    }
}

// ------------- conversions --------------------------------------------------
__global__ __launch_bounds__(256) void f2h4(const float* __restrict__ in,
                                            unsigned short* __restrict__ out, int n4) {
    int i = blockIdx.x * 256 + threadIdx.x;
    if (i >= n4) return;
    float4 v = reinterpret_cast<const float4*>(in)[i];
    ushort4 o;
    o.x = f2h(v.x); o.y = f2h(v.y); o.z = f2h(v.z); o.w = f2h(v.w);
    reinterpret_cast<ushort4*>(out)[i] = o;
}

// Fused weight prep: Wt1[r][n][k], Wt2[r][n][k], Woutt[n][k] in one launch.
__global__ __launch_bounds__(256) void wprep_kernel(const float* __restrict__ W1,
                                                    const float* __restrict__ W2,
                                                    const float* __restrict__ Wout,
                                                    unsigned short* __restrict__ Wt,
                                                    unsigned short* __restrict__ Woutt) {
    int idx = blockIdx.x * 256 + threadIdx.x;
    const int NW = 2 * RR * 65536;
    if (idx < NW) {
        int lyr = idx >= RR * 65536;
        int rem2 = idx - lyr * RR * 65536;
        int r = rem2 >> 16, rem = rem2 & 65535;
        int n = rem >> 8, k = rem & 255;
        const float* W = lyr ? W2 : W1;
        Wt[idx] = f2h(W[(r << 16) + (k << 8) + n]);
    } else if (idx < NW + 65536) {
        int rem = idx - NW;
        int n = rem >> 8, k = rem & 255;
        Woutt[rem] = (n < CC) ? f2h(Wout[k * CC + n]) : (unsigned short)0;
    }
}

// ================= CSR build (once per call, all 3 relations) ================
__global__ __launch_bounds__(256) void hist_kernel(const int* __restrict__ dst,
                                                   int* __restrict__ deg) {
    int i = blockIdx.x * 256 + threadIdx.x;
    if (i >= RR * EE) return;
    int r = i / EE;
    atomicAdd(&deg[r * NN + dst[i]], 1);
}

__global__ __launch_bounds__(256) void scan_block(const int* __restrict__ deg,
                                                  int* __restrict__ rowptr,
                                                  int* __restrict__ bsum) {
    __shared__ int sh[256];
    int r = blockIdx.y, b = blockIdx.x, t = threadIdx.x;
    int base = b * 1024;
    int v[4];
#pragma unroll
    for (int j = 0; j < 4; ++j) {
        int idx = base + t * 4 + j;
        v[j] = (idx < NN) ? deg[r * NN + idx] : 0;
    }
    int tsum = v[0] + v[1] + v[2] + v[3];
    sh[t] = tsum;
    __syncthreads();
    for (int off = 1; off < 256; off <<= 1) {
        int x = (t >= off) ? sh[t - off] : 0;
        __syncthreads();
        sh[t] += x;
        __syncthreads();
    }
    int run = sh[t] - tsum;
#pragma unroll
    for (int j = 0; j < 4; ++j) {
        int idx = base + t * 4 + j;
        if (idx < NN) rowptr[r * (NN + 1) + idx] = run;
        run += v[j];
    }
    if (t == 255) bsum[r * NB + b] = run;
}

__global__ void scan_bsum(int* __restrict__ bsum, int* __restrict__ rowptr) {
    int r = threadIdx.x;
    if (r >= RR) return;
    int run = 0;
    for (int b = 0; b < NB; ++b) {
        int x = bsum[r * NB + b];
        bsum[r * NB + b] = run;
        run += x;
    }
    rowptr[r * (NN + 1) + NN] = run;
}

__global__ __launch_bounds__(256) void add_off(int* __restrict__ rowptr,
                                               const int* __restrict__ bsum) {
    int r = blockIdx.y, b = blockIdx.x, t = threadIdx.x;
    int o = bsum[r * NB + b];
#pragma unroll
    for (int j = 0; j < 4; ++j) {
        int idx = b * 1024 + t * 4 + j;
        if (idx < NN) rowptr[r * (NN + 1) + idx] += o;
    }
}

__global__ __launch_bounds__(256) void fill_kernel(const int* __restrict__ src,
                                                   const int* __restrict__ dst,
                                                   const int* __restrict__ rowptr,
                                                   int* __restrict__ cursor,
                                                   int* __restrict__ csrc) {
    int i = blockIdx.x * 256 + threadIdx.x;
    if (i >= RR * EE) return;
    int r = i / EE;
    int d = dst[i], s = src[i];
    int pos = rowptr[r * (NN + 1) + d] + atomicAdd(&cursor[r * NN + d], 1);
    csrc[(size_t)r * EE + pos] = s;
}

// ========== merged 3-relation softmax+aggregation: one wave per dst ==========
// R17-proven body: 4-deep unroll over exact quads + <=3-edge scalar tail.
template<int RELU>
__global__ __launch_bounds__(256) void agg3_kernel(const int* __restrict__ csrc,      // [3][EE]
                                                   const int* __restrict__ rowptr,    // [3][NN+1]
                                                   const float* __restrict__ el,      // [3][NN*4]
                                                   const float* __restrict__ er,      // [3][NN*4]
                                                   const unsigned short* __restrict__ feat, // [3][NN*256]
                                                   const float* __restrict__ brel,    // [3][256]
                                                   unsigned short* __restrict__ hout) {
    int wid = (blockIdx.x * 256 + threadIdx.x) >> 6;
    int lane = threadIdx.x & 63;
    if (wid >= NN) return;
    int d = wid;
    int h = lane >> 4;
    int f0 = lane * 4;

    float4 bA = *reinterpret_cast<const float4*>(brel + f0);
    float4 bB = *reinterpret_cast<const float4*>(brel + 256 + f0);
    float4 bC = *reinterpret_cast<const float4*>(brel + 512 + f0);
    float4 cur = make_float4(bA.x + bB.x + bC.x, bA.y + bB.y + bC.y,
                             bA.z + bB.z + bC.z, bA.w + bB.w + bC.w);

#pragma unroll
    for (int r = 0; r < RR; ++r) {
        int p0 = rowptr[r * (NN + 1) + d], p1 = rowptr[r * (NN + 1) + d + 1];
        if (p0 == p1) continue;
        float erd = er[(size_t)r * NN * 4 + d * 4 + h];
        const float* elr = el + (size_t)r * NN * 4;
        const unsigned short* fr = feat + (size_t)r * NN * 256;
        const int* cs = csrc + (size_t)r * EE;

        h2f16 aA01 = (h2f16)0, aA23 = (h2f16)0;   // chain A (edges 0,2)
        h2f16 aB01 = (h2f16)0, aB23 = (h2f16)0;   // chain B (edges 1,3)
        float zs = 0.f;
        int nq = (p1 - p0) & ~3;                  // full quads
        int pq = p0 + nq;
        for (int p = p0; p < pq; p += 4) {
            int s0 = cs[p], s1 = cs[p + 1], s2 = cs[p + 2], s3 = cs[p + 3];
            uint2 fA = *reinterpret_cast<const uint2*>(fr + (size_t)s0 * 256 + f0);
            uint2 fB = *reinterpret_cast<const uint2*>(fr + (size_t)s1 * 256 + f0);
            uint2 fC = *reinterpret_cast<const uint2*>(fr + (size_t)s2 * 256 + f0);
            uint2 fD = *reinterpret_cast<const uint2*>(fr + (size_t)s3 * 256 + f0);
            float v0 = elr[s0 * 4 + h] + erd;
            float v1 = elr[s1 * 4 + h] + erd;
            float v2 = elr[s2 * 4 + h] + erd;
            float v3 = elr[s3 * 4 + h] + erd;
            v0 = v0 > 0.f ? v0 : 0.2f * v0;
            v1 = v1 > 0.f ? v1 : 0.2f * v1;
            v2 = v2 > 0.f ? v2 : 0.2f * v2;
            v3 = v3 > 0.f ? v3 : 0.2f * v3;
            float w0 = __expf(v0), w1 = __expf(v1);
            float w2 = __expf(v2), w3 = __expf(v3);
            zs += (w0 + w1) + (w2 + w3);
            _Float16 h0 = (_Float16)w0, h1 = (_Float16)w1;
            _Float16 h2 = (_Float16)w2, h3 = (_Float16)w3;
            h2f16 wp0 = (h2f16){h0, h0}, wp1 = (h2f16){h1, h1};
            h2f16 wp2 = (h2f16){h2, h2}, wp3 = (h2f16){h3, h3};
            aA01 += wp0 * __builtin_bit_cast(h2f16, fA.x);
            aA23 += wp0 * __builtin_bit_cast(h2f16, fA.y);
            aB01 += wp1 * __builtin_bit_cast(h2f16, fB.x);
            aB23 += wp1 * __builtin_bit_cast(h2f16, fB.y);
            aA01 += wp2 * __builtin_bit_cast(h2f16, fC.x);
            aA23 += wp2 * __builtin_bit_cast(h2f16, fC.y);
            aB01 += wp3 * __builtin_bit_cast(h2f16, fD.x);
            aB23 += wp3 * __builtin_bit_cast(h2f16, fD.y);
        }
        for (int p = pq; p < p1; ++p) {           // 0..3 tail edges
            int s0 = cs[p];
            uint2 fA = *reinterpret_cast<const uint2*>(fr + (size_t)s0 * 256 + f0);
            float v0 = elr[s0 * 4 + h] + erd;
            v0 = v0 > 0.f ? v0 : 0.2f * v0;
            float w0 = __expf(v0);
            zs += w0;
            _Float16 h0 = (_Float16)w0;
            h2f16 wp0 = (h2f16){h0, h0};
            aA01 += wp0 * __builtin_bit_cast(h2f16, fA.x);
            aA23 += wp0 * __builtin_bit_cast(h2f16, fA.y);
        }
        float inv = 1.f / zs;
        cur.x += ((float)aA01[0] + (float)aB01[0]) * inv;
        cur.y += ((float)aA01[1] + (float)aB01[1]) * inv;
        cur.z += ((float)aA23[0] + (float)aB23[0]) * inv;
        cur.w += ((float)aA23[1] + (float)aB23[1]) * inv;
    }
    if (RELU) {
        cur.x = fmaxf(cur.x, 0.f); cur.y = fmaxf(cur.y, 0.f);
        cur.z = fmaxf(cur.z, 0.f); cur.w = fmaxf(cur.w, 0.f);
    }
    ushort4 o;
    o.x = f2h(cur.x); o.y = f2h(cur.y); o.z = f2h(cur.z); o.w = f2h(cur.w);
    *reinterpret_cast<ushort4*>(hout + (size_t)d * 256 + f0) = o;
}

extern "C" void kernel_launch(void* const* d_in, const int* in_sizes, int n_in,
                              void* d_out, int out_size, void* d_ws, size_t ws_size,
                              hipStream_t stream) {
    const float* x    = (const float*)d_in[0];
    const int*   src  = (const int*)d_in[1];
    const int*   dst  = (const int*)d_in[2];
    const float* W1   = (const float*)d_in[3];
    const float* al1  = (const float*)d_in[4];
    const float* ar1  = (const float*)d_in[5];
    const float* b1   = (const float*)d_in[6];
    const float* W2   = (const float*)d_in[7];
    const float* al2  = (const float*)d_in[8];
    const float* ar2  = (const float*)d_in[9];
    const float* b2   = (const float*)d_in[10];
    const float* Wout = (const float*)d_in[11];
    const float* bout = (const float*)d_in[12];
    float* out = (float*)d_out;

    // ---- workspace layout: every sub-buffer 256B-aligned ----
    char* base = (char*)d_ws;
    size_t off = 0;
    auto alloc = [&](size_t bytes) -> char* {
        char* p = base + off;
        off = (off + bytes + 255) & ~(size_t)255;
        return p;
    };
    size_t NF = (size_t)NN * HFF;                 // 25.6M elements
    unsigned short* feath = (unsigned short*)alloc(RR * NF * 2);  // fp16 feat, 3 relations
    float* el   = (float*)alloc((size_t)RR * NN * NH * 4);
    float* er   = (float*)alloc((size_t)RR * NN * NH * 4);
    int* deg    = (int*)alloc((size_t)RR * NN * 4 * 2);       // deg + cursor contiguous
    int* cursor = deg + (size_t)RR * NN;
    int* rowptr = (int*)alloc((size_t)RR * (NN + 1) * 4);
    int* bsum   = (int*)alloc((size_t)RR * NB * 4);
    int* csrc   = (int*)alloc((size_t)RR * EE * 4);
    unsigned short* xh    = (unsigned short*)alloc(NF * 2);   // x_f16 / h1_f16 / h2_f16
    unsigned short* wth   = (unsigned short*)alloc((size_t)2 * RR * 65536 * 2);
    unsigned short* wouth = (unsigned short*)alloc((size_t)65536 * 2);

    int n4Blocks = (int)((NF / 4 + 255) / 256);
    int reBlocks = (RR * EE + 255) / 256;
    int aggBlocks = (NN * 64 + 255) / 256;        // one wave per dst
    dim3 pgrid(6, ROWG);                          // col tile fastest; 4 panels/block
    dim3 ogrid(2, ROWG);                          // output linear
    int wpBlocks = (2 * RR * 65536 + 65536) / 256;

    // ---- CSR build (shared by both layers) ----
    hipMemsetAsync(deg, 0, (size_t)RR * NN * sizeof(int) * 2, stream);
    hist_kernel<<<reBlocks, 256, 0, stream>>>(dst, deg);
    scan_block<<<dim3(NB, RR), 256, 0, stream>>>(deg, rowptr, bsum);
    scan_bsum<<<1, 64, 0, stream>>>(bsum, rowptr);
    add_off<<<dim3(NB, RR), 256, 0, stream>>>(rowptr, bsum);
    fill_kernel<<<reBlocks, 256, 0, stream>>>(src, dst, rowptr, cursor, csrc);

    // ---- input conversion + all weight transposes up front ----
    f2h4<<<n4Blocks, 256, 0, stream>>>(x, xh, (int)(NF / 4));
    wprep_kernel<<<wpBlocks, 256, 0, stream>>>(W1, W2, Wout, wth, wouth);

    for (int layer = 0; layer < 2; ++layer) {
        const float* al = layer ? al2 : al1;
        const float* ar = layer ? ar2 : ar1;
        const float* b  = layer ? b2 : b1;
        const unsigned short* wl = wth + (size_t)layer * RR * 65536;

        mfma_gemm<1><<<pgrid, 256, 0, stream>>>(xh, wl, nullptr,
                                                nullptr, feath, al, ar, el, er, NN);
        if (layer == 0)
            agg3_kernel<1><<<aggBlocks, 256, 0, stream>>>(csrc, rowptr, el, er, feath, b, xh);
        else
            agg3_kernel<0><<<aggBlocks, 256, 0, stream>>>(csrc, rowptr, el, er, feath, b, xh);
    }

    // ---- output linear (+ bout) ----
    mfma_gemm<0><<<ogrid, 256, 0, stream>>>(xh, wouth, bout, out, nullptr,
                                            nullptr, nullptr, nullptr, nullptr, NN);
}

// Round 20
// 811.264 us; speedup vs baseline: 1.0427x; 1.0427x over previous
//
#include <hip/hip_runtime.h>
#include <hip/hip_bf16.h>

#define NN 100000
#define EE 600000
#define RR 3
#define INF 256
#define HFF 256
#define NH 4
#define DD 64
#define CC 153
#define NB 98   // ceil(NN/1024)

typedef __attribute__((ext_vector_type(8))) _Float16 f16x8;
typedef __attribute__((ext_vector_type(2))) _Float16 h2f16;
typedef __attribute__((ext_vector_type(4))) float f32x4;

#define GLDS(g, l) __builtin_amdgcn_global_load_lds((const __attribute__((address_space(1))) void*)(g), \
                                                    (__attribute__((address_space(3))) void*)(l), 16, 0, 0)

static __device__ __forceinline__ unsigned short f2h(float x) {
    _Float16 h = (_Float16)x;
    return __builtin_bit_cast(unsigned short, h);
}

// ================= f16 MFMA GEMM, 128x128 tile, BK=64, 4 waves ================
// GM=0: C32[M,CC] = A@Bt + bias  (final linear), grid (782,2)
// GM=1: merged 3-relation projection, grid (782,6); Bt=[768][256];
//       fp16 feat via LDS-staged coalesced store; fused el/er epilogue.
template<int GM>
__global__ __launch_bounds__(256) void mfma_gemm(const unsigned short* __restrict__ A,
                                                 const unsigned short* __restrict__ Bt,
                                                 const float* __restrict__ bias,
                                                 float* __restrict__ C32,
                                                 unsigned short* __restrict__ C16,
                                                 const float* __restrict__ al,
                                                 const float* __restrict__ ar,
                                                 float* __restrict__ el,
                                                 float* __restrict__ er,
                                                 int M) {
    __shared__ __align__(1024) char lds[32768];   // A tile 16KB | B tile 16KB
    const int tid = threadIdx.x;
    const int lane = tid & 63;
    const int w = tid >> 6;
    const int wr = w >> 1, wc = w & 1;
    const int bm = blockIdx.x * 128;
    const int bn = blockIdx.y * 128;

    f32x4 acc[4][4] = {};

    const int lrow8 = lane >> 3;
    const int cbs = ((lane & 7) << 4) ^ ((lrow8 & 7) << 4);
    const int cbase = w * 8;
    const bool isA = (w < 2);

    const char* gA = (const char*)A;
    const char* gB = (const char*)Bt;

    for (int step = 0; step < 4; ++step) {
        const int k0b = step * 128;              // 64 f16 per K-step
#pragma unroll
        for (int i = 0; i < 8; ++i) {
            int c = cbase + i;
            char* lptr = &lds[c * 1024];
            if (isA) {
                int R = c * 8 + lrow8;
                int grow = bm + R; if (grow >= M) grow = M - 1;
                GLDS(gA + (size_t)grow * 512 + k0b + cbs, lptr);
            } else {
                int nIdx = (c - 16) * 8 + lrow8;
                GLDS(gB + (size_t)(bn + nIdx) * 512 + k0b + cbs, lptr);
            }
        }
        __syncthreads();
#pragma unroll
        for (int kk = 0; kk < 2; ++kk) {
            f16x8 af[4], bfr[4];
            const int o = kk * 64 + ((lane >> 4) << 4);
#pragma unroll
            for (int m = 0; m < 4; ++m) {
                int R = wr * 64 + m * 16 + (lane & 15);
                af[m] = *reinterpret_cast<const f16x8*>(&lds[R * 128 + (o ^ ((R & 7) << 4))]);
            }
#pragma unroll
            for (int n = 0; n < 4; ++n) {
                int Rn = wc * 64 + n * 16 + (lane & 15);
                bfr[n] = *reinterpret_cast<const f16x8*>(&lds[16384 + Rn * 128 + (o ^ ((Rn & 7) << 4))]);
            }
#pragma unroll
            for (int m = 0; m < 4; ++m)
#pragma unroll
                for (int n = 0; n < 4; ++n)
                    acc[m][n] = __builtin_amdgcn_mfma_f32_16x16x32_f16(af[m], bfr[n], acc[m][n], 0, 0, 0);
        }
        __syncthreads();
    }

    const int rb = bm + wr * 64 + ((lane >> 4) << 2);

    if (GM == 0) {
        const int cb2 = bn + wc * 64 + (lane & 15);
#pragma unroll
        for (int m = 0; m < 4; ++m)
#pragma unroll
            for (int n = 0; n < 4; ++n) {
                int col = cb2 + n * 16;
                if (col < CC) {
                    float bb = bias[col];
#pragma unroll
                    for (int j = 0; j < 4; ++j) {
                        int row = rb + m * 16 + j;
                        if (row < M) C32[(size_t)row * CC + col] = acc[m][n][j] + bb;
                    }
                }
            }
    } else {
        // ---- fused el/er: wave's 64 cols == one head of one relation ----
        const int c0 = bn + wc * 64;
        const int rh = c0 >> 6;                  // r*4 + h, 0..11
        const int rw = rh >> 2;                  // relation of this wave
        const int h  = rh & 3;
        float alv[4], arv[4];
#pragma unroll
        for (int n = 0; n < 4; ++n) {
            alv[n] = al[rh * 64 + n * 16 + (lane & 15)];
            arv[n] = ar[rh * 64 + n * 16 + (lane & 15)];
        }
#pragma unroll
        for (int m = 0; m < 4; ++m)
#pragma unroll
            for (int j = 0; j < 4; ++j) {
                float pl = acc[m][0][j] * alv[0] + acc[m][1][j] * alv[1]
                         + acc[m][2][j] * alv[2] + acc[m][3][j] * alv[3];
                float pr = acc[m][0][j] * arv[0] + acc[m][1][j] * arv[1]
                         + acc[m][2][j] * arv[2] + acc[m][3][j] * arv[3];
#pragma unroll
                for (int o2 = 1; o2 < 16; o2 <<= 1) {
                    pl += __shfl_xor(pl, o2);
                    pr += __shfl_xor(pr, o2);
                }
                int row = rb + m * 16 + j;
                if ((lane & 15) == 0 && row < M) {
                    el[(size_t)rw * NN * 4 + row * 4 + h] = pl;
                    er[(size_t)rw * NN * 4 + row * 4 + h] = pr;
                }
            }
        // ---- fp16 feat: stage in LDS (XOR swizzle), store coalesced ----
        __syncthreads();     // all MFMA LDS reads done; safe to reuse lds
        unsigned short* l16 = (unsigned short*)lds;
#pragma unroll
        for (int m = 0; m < 4; ++m)
#pragma unroll
            for (int n = 0; n < 4; ++n)
#pragma unroll
                for (int j = 0; j < 4; ++j) {
                    int row = wr * 64 + m * 16 + ((lane >> 4) << 2) + j;
                    int colb = (wc * 64 + n * 16 + (lane & 15)) * 2;
                    int addr = row * 256 + (colb ^ (((row >> 2) & 7) << 5));
                    l16[addr >> 1] = f2h(acc[m][n][j]);
                }
        __syncthreads();
        const int rblk = bn >> 8;                // relation of this tile
        const int bnc  = bn & 255;               // col base within relation
        const size_t NFE = (size_t)NN * 256;
#pragma unroll
        for (int i = 0; i < 8; ++i) {
            int seg = w * 8 + i;                 // 0..31, 1KB segments
            int row = seg * 4 + (lane >> 4);
            int colb = (lane & 15) * 16;
            int addr = row * 256 + (colb ^ (((row >> 2) & 7) << 5));
            uint4 v = *reinterpret_cast<const uint4*>(&lds[addr]);
            int grow = bm + row;
            if (grow < M) {
                unsigned short* gp = C16 + (size_t)rblk * NFE + (size_t)grow * 256 + bnc + (lane & 15) * 8;
                *reinterpret_cast<uint4*>(gp) = v;
            }
        }
    }
}

// ------------- conversions --------------------------------------------------
__global__ __launch_bounds__(256) void f2h4(const float* __restrict__ in,
                                            unsigned short* __restrict__ out, int n4) {
    int i = blockIdx.x * 256 + threadIdx.x;
    if (i >= n4) return;
    float4 v = reinterpret_cast<const float4*>(in)[i];
    ushort4 o;
    o.x = f2h(v.x); o.y = f2h(v.y); o.z = f2h(v.z); o.w = f2h(v.w);
    reinterpret_cast<ushort4*>(out)[i] = o;
}

// Fused weight prep: Wt1[r][n][k], Wt2[r][n][k], Woutt[n][k] in one launch.
__global__ __launch_bounds__(256) void wprep_kernel(const float* __restrict__ W1,
                                                    const float* __restrict__ W2,
                                                    const float* __restrict__ Wout,
                                                    unsigned short* __restrict__ Wt,
                                                    unsigned short* __restrict__ Woutt) {
    int idx = blockIdx.x * 256 + threadIdx.x;
    const int NW = 2 * RR * 65536;
    if (idx < NW) {
        int lyr = idx >= RR * 65536;
        int rem2 = idx - lyr * RR * 65536;
        int r = rem2 >> 16, rem = rem2 & 65535;
        int n = rem >> 8, k = rem & 255;
        const float* W = lyr ? W2 : W1;
        Wt[idx] = f2h(W[(r << 16) + (k << 8) + n]);
    } else if (idx < NW + 65536) {
        int rem = idx - NW;
        int n = rem >> 8, k = rem & 255;
        Woutt[rem] = (n < CC) ? f2h(Wout[k * CC + n]) : (unsigned short)0;
    }
}

// ================= CSR build (once per call, all 3 relations) ================
__global__ __launch_bounds__(256) void hist_kernel(const int* __restrict__ dst,
                                                   int* __restrict__ deg) {
    int i = blockIdx.x * 256 + threadIdx.x;
    if (i >= RR * EE) return;
    int r = i / EE;
    atomicAdd(&deg[r * NN + dst[i]], 1);
}

__global__ __launch_bounds__(256) void scan_block(const int* __restrict__ deg,
                                                  int* __restrict__ rowptr,
                                                  int* __restrict__ bsum) {
    __shared__ int sh[256];
    int r = blockIdx.y, b = blockIdx.x, t = threadIdx.x;
    int base = b * 1024;
    int v[4];
#pragma unroll
    for (int j = 0; j < 4; ++j) {
        int idx = base + t * 4 + j;
        v[j] = (idx < NN) ? deg[r * NN + idx] : 0;
    }
    int tsum = v[0] + v[1] + v[2] + v[3];
    sh[t] = tsum;
    __syncthreads();
    for (int off = 1; off < 256; off <<= 1) {
        int x = (t >= off) ? sh[t - off] : 0;
        __syncthreads();
        sh[t] += x;
        __syncthreads();
    }
    int run = sh[t] - tsum;
#pragma unroll
    for (int j = 0; j < 4; ++j) {
        int idx = base + t * 4 + j;
        if (idx < NN) rowptr[r * (NN + 1) + idx] = run;
        run += v[j];
    }
    if (t == 255) bsum[r * NB + b] = run;
}

__global__ void scan_bsum(int* __restrict__ bsum, int* __restrict__ rowptr) {
    int r = threadIdx.x;
    if (r >= RR) return;
    int run = 0;
    for (int b = 0; b < NB; ++b) {
        int x = bsum[r * NB + b];
        bsum[r * NB + b] = run;
        run += x;
    }
    rowptr[r * (NN + 1) + NN] = run;
}

__global__ __launch_bounds__(256) void add_off(int* __restrict__ rowptr,
                                               const int* __restrict__ bsum) {
    int r = blockIdx.y, b = blockIdx.x, t = threadIdx.x;
    int o = bsum[r * NB + b];
#pragma unroll
    for (int j = 0; j < 4; ++j) {
        int idx = b * 1024 + t * 4 + j;
        if (idx < NN) rowptr[r * (NN + 1) + idx] += o;
    }
}

__global__ __launch_bounds__(256) void fill_kernel(const int* __restrict__ src,
                                                   const int* __restrict__ dst,
                                                   const int* __restrict__ rowptr,
                                                   int* __restrict__ cursor,
                                                   int* __restrict__ csrc) {
    int i = blockIdx.x * 256 + threadIdx.x;
    if (i >= RR * EE) return;
    int r = i / EE;
    int d = dst[i], s = src[i];
    int pos = rowptr[r * (NN + 1) + d] + atomicAdd(&cursor[r * NN + d], 1);
    csrc[(size_t)r * EE + pos] = s;
}

// ========== merged 3-relation softmax+aggregation: one wave per dst ==========
// 4-deep unroll over exact quads + <=3-edge scalar tail.
template<int RELU>
__global__ __launch_bounds__(256) void agg3_kernel(const int* __restrict__ csrc,      // [3][EE]
                                                   const int* __restrict__ rowptr,    // [3][NN+1]
                                                   const float* __restrict__ el,      // [3][NN*4]
                                                   const float* __restrict__ er,      // [3][NN*4]
                                                   const unsigned short* __restrict__ feat, // [3][NN*256]
                                                   const float* __restrict__ brel,    // [3][256]
                                                   unsigned short* __restrict__ hout) {
    int wid = (blockIdx.x * 256 + threadIdx.x) >> 6;
    int lane = threadIdx.x & 63;
    if (wid >= NN) return;
    int d = wid;
    int h = lane >> 4;
    int f0 = lane * 4;

    float4 bA = *reinterpret_cast<const float4*>(brel + f0);
    float4 bB = *reinterpret_cast<const float4*>(brel + 256 + f0);
    float4 bC = *reinterpret_cast<const float4*>(brel + 512 + f0);
    float4 cur = make_float4(bA.x + bB.x + bC.x, bA.y + bB.y + bC.y,
                             bA.z + bB.z + bC.z, bA.w + bB.w + bC.w);

#pragma unroll
    for (int r = 0; r < RR; ++r) {
        int p0 = rowptr[r * (NN + 1) + d], p1 = rowptr[r * (NN + 1) + d + 1];
        if (p0 == p1) continue;
        float erd = er[(size_t)r * NN * 4 + d * 4 + h];
        const float* elr = el + (size_t)r * NN * 4;
        const unsigned short* fr = feat + (size_t)r * NN * 256;
        const int* cs = csrc + (size_t)r * EE;

        h2f16 aA01 = (h2f16)0, aA23 = (h2f16)0;   // chain A (edges 0,2)
        h2f16 aB01 = (h2f16)0, aB23 = (h2f16)0;   // chain B (edges 1,3)
        float zs = 0.f;
        int nq = (p1 - p0) & ~3;                  // full quads
        int pq = p0 + nq;
        for (int p = p0; p < pq; p += 4) {
            int s0 = cs[p], s1 = cs[p + 1], s2 = cs[p + 2], s3 = cs[p + 3];
            uint2 fA = *reinterpret_cast<const uint2*>(fr + (size_t)s0 * 256 + f0);
            uint2 fB = *reinterpret_cast<const uint2*>(fr + (size_t)s1 * 256 + f0);
            uint2 fC = *reinterpret_cast<const uint2*>(fr + (size_t)s2 * 256 + f0);
            uint2 fD = *reinterpret_cast<const uint2*>(fr + (size_t)s3 * 256 + f0);
            float v0 = elr[s0 * 4 + h] + erd;
            float v1 = elr[s1 * 4 + h] + erd;
            float v2 = elr[s2 * 4 + h] + erd;
            float v3 = elr[s3 * 4 + h] + erd;
            v0 = v0 > 0.f ? v0 : 0.2f * v0;
            v1 = v1 > 0.f ? v1 : 0.2f * v1;
            v2 = v2 > 0.f ? v2 : 0.2f * v2;
            v3 = v3 > 0.f ? v3 : 0.2f * v3;
            float w0 = __expf(v0), w1 = __expf(v1);
            float w2 = __expf(v2), w3 = __expf(v3);
            zs += (w0 + w1) + (w2 + w3);
            _Float16 h0 = (_Float16)w0, h1 = (_Float16)w1;
            _Float16 h2 = (_Float16)w2, h3 = (_Float16)w3;
            h2f16 wp0 = (h2f16){h0, h0}, wp1 = (h2f16){h1, h1};
            h2f16 wp2 = (h2f16){h2, h2}, wp3 = (h2f16){h3, h3};
            aA01 += wp0 * __builtin_bit_cast(h2f16, fA.x);
            aA23 += wp0 * __builtin_bit_cast(h2f16, fA.y);
            aB01 += wp1 * __builtin_bit_cast(h2f16, fB.x);
            aB23 += wp1 * __builtin_bit_cast(h2f16, fB.y);
            aA01 += wp2 * __builtin_bit_cast(h2f16, fC.x);
            aA23 += wp2 * __builtin_bit_cast(h2f16, fC.y);
            aB01 += wp3 * __builtin_bit_cast(h2f16, fD.x);
            aB23 += wp3 * __builtin_bit_cast(h2f16, fD.y);
        }
        for (int p = pq; p < p1; ++p) {           // 0..3 tail edges
            int s0 = cs[p];
            uint2 fA = *reinterpret_cast<const uint2*>(fr + (size_t)s0 * 256 + f0);
            float v0 = elr[s0 * 4 + h] + erd;
            v0 = v0 > 0.f ? v0 : 0.2f * v0;
            float w0 = __expf(v0);
            zs += w0;
            _Float16 h0 = (_Float16)w0;
            h2f16 wp0 = (h2f16){h0, h0};
            aA01 += wp0 * __builtin_bit_cast(h2f16, fA.x);
            aA23 += wp0 * __builtin_bit_cast(h2f16, fA.y);
        }
        float inv = 1.f / zs;
        cur.x += ((float)aA01[0] + (float)aB01[0]) * inv;
        cur.y += ((float)aA01[1] + (float)aB01[1]) * inv;
        cur.z += ((float)aA23[0] + (float)aB23[0]) * inv;
        cur.w += ((float)aA23[1] + (float)aB23[1]) * inv;
    }
    if (RELU) {
        cur.x = fmaxf(cur.x, 0.f); cur.y = fmaxf(cur.y, 0.f);
        cur.z = fmaxf(cur.z, 0.f); cur.w = fmaxf(cur.w, 0.f);
    }
    ushort4 o;
    o.x = f2h(cur.x); o.y = f2h(cur.y); o.z = f2h(cur.z); o.w = f2h(cur.w);
    *reinterpret_cast<ushort4*>(hout + (size_t)d * 256 + f0) = o;
}

extern "C" void kernel_launch(void* const* d_in, const int* in_sizes, int n_in,
                              void* d_out, int out_size, void* d_ws, size_t ws_size,
                              hipStream_t stream) {
    const float* x    = (const float*)d_in[0];
    const int*   src  = (const int*)d_in[1];
    const int*   dst  = (const int*)d_in[2];
    const float* W1   = (const float*)d_in[3];
    const float* al1  = (const float*)d_in[4];
    const float* ar1  = (const float*)d_in[5];
    const float* b1   = (const float*)d_in[6];
    const float* W2   = (const float*)d_in[7];
    const float* al2  = (const float*)d_in[8];
    const float* ar2  = (const float*)d_in[9];
    const float* b2   = (const float*)d_in[10];
    const float* Wout = (const float*)d_in[11];
    const float* bout = (const float*)d_in[12];
    float* out = (float*)d_out;

    // ---- workspace layout: every sub-buffer 256B-aligned ----
    char* base = (char*)d_ws;
    size_t off = 0;
    auto alloc = [&](size_t bytes) -> char* {
        char* p = base + off;
        off = (off + bytes + 255) & ~(size_t)255;
        return p;
    };
    size_t NF = (size_t)NN * HFF;                 // 25.6M elements
    unsigned short* feath = (unsigned short*)alloc(RR * NF * 2);  // fp16 feat, 3 relations
    float* el   = (float*)alloc((size_t)RR * NN * NH * 4);
    float* er   = (float*)alloc((size_t)RR * NN * NH * 4);
    int* deg    = (int*)alloc((size_t)RR * NN * 4 * 2);       // deg + cursor contiguous
    int* cursor = deg + (size_t)RR * NN;
    int* rowptr = (int*)alloc((size_t)RR * (NN + 1) * 4);
    int* bsum   = (int*)alloc((size_t)RR * NB * 4);
    int* csrc   = (int*)alloc((size_t)RR * EE * 4);
    unsigned short* xh    = (unsigned short*)alloc(NF * 2);   // x_f16 / h1_f16 / h2_f16
    unsigned short* wth   = (unsigned short*)alloc((size_t)2 * RR * 65536 * 2);
    unsigned short* wouth = (unsigned short*)alloc((size_t)65536 * 2);

    int n4Blocks = (int)((NF / 4 + 255) / 256);
    int reBlocks = (RR * EE + 255) / 256;
    int aggBlocks = (NN * 64 + 255) / 256;        // one wave per dst
    dim3 pgrid((NN + 127) / 128, 6);              // merged 3-relation projection
    dim3 ogrid((NN + 127) / 128, 2);              // output linear
    int wpBlocks = (2 * RR * 65536 + 65536) / 256;

    // ---- CSR build (shared by both layers) ----
    hipMemsetAsync(deg, 0, (size_t)RR * NN * sizeof(int) * 2, stream);
    hist_kernel<<<reBlocks, 256, 0, stream>>>(dst, deg);
    scan_block<<<dim3(NB, RR), 256, 0, stream>>>(deg, rowptr, bsum);
    scan_bsum<<<1, 64, 0, stream>>>(bsum, rowptr);
    add_off<<<dim3(NB, RR), 256, 0, stream>>>(rowptr, bsum);
    fill_kernel<<<reBlocks, 256, 0, stream>>>(src, dst, rowptr, cursor, csrc);

    // ---- input conversion + all weight transposes up front ----
    f2h4<<<n4Blocks, 256, 0, stream>>>(x, xh, (int)(NF / 4));
    wprep_kernel<<<wpBlocks, 256, 0, stream>>>(W1, W2, Wout, wth, wouth);

    for (int layer = 0; layer < 2; ++layer) {
        const float* al = layer ? al2 : al1;
        const float* ar = layer ? ar2 : ar1;
        const float* b  = layer ? b2 : b1;
        const unsigned short* wl = wth + (size_t)layer * RR * 65536;

        mfma_gemm<1><<<pgrid, 256, 0, stream>>>(xh, wl, nullptr,
                                                nullptr, feath, al, ar, el, er, NN);
        if (layer == 0)
            agg3_kernel<1><<<aggBlocks, 256, 0, stream>>>(csrc, rowptr, el, er, feath, b, xh);
        else
            agg3_kernel<0><<<aggBlocks, 256, 0, stream>>>(csrc, rowptr, el, er, feath, b, xh);
    }

    // ---- output linear (+ bout) ----
    mfma_gemm<0><<<ogrid, 256, 0, stream>>>(xh, wouth, bout, out, nullptr,
                                            nullptr, nullptr, nullptr, nullptr, NN);
}